// Round 6
// baseline (253.260 us; speedup 1.0000x reference)
//
#include <hip/hip_runtime.h>
#include <math.h>

#define B_    4096
#define N_    10
#define DIN_  32
#define D_    128
#define PHI_  256
#define RHO_  128
#define L_    3
#define EPS_  1e-5f

// ---- bf16 helpers (bits in short) ----
__device__ __forceinline__ short f2bs(float f) {            // f32 -> bf16 RNE
    unsigned u = __float_as_uint(f);
    u += 0x7fffu + ((u >> 16) & 1u);
    return (short)(u >> 16);
}
__device__ __forceinline__ float bs2f(short s) {
    return __uint_as_float(((unsigned)(unsigned short)s) << 16);
}

typedef short bf16x8 __attribute__((ext_vector_type(8)));
typedef float f32x4  __attribute__((ext_vector_type(4)));
typedef float v2f    __attribute__((ext_vector_type(2)));

__device__ __forceinline__ v2f splat2(float s) { v2f r; r.x = s; r.y = s; return r; }
__device__ __forceinline__ v2f fma2(v2f a, v2f b, v2f c) { return __builtin_elementwise_fma(a, b, c); }

// ---- d_ws layout (bf16 elements). Fragment unit = 64 lanes x 8 el = 512 el.
// For matrix W[K][N]: frag (nt,ks) at ((nt*KS+ks)*64+lane)*8, lane holds
// W[ks*32+(lane>>4)*8+j][nt*16+(lane&15)], j=0..7  (B-operand layout, 16x16x32)
#define WS_WE1 0
#define WS_WE2 4096
#define WS_RGW 20480
#define WS_RGR 118784
#define WS_L1  167936
#define WS_L2  217088
#define WS_P1  266240
#define WS_P2  299008
#define WS_R1  364544

// ================= prep kernel: fp32 weights -> bf16 B-fragments ==========
__global__ __launch_bounds__(64)
void prep_weights(const float* __restrict__ We1, const float* __restrict__ We2,
                  const float* __restrict__ rgw, const float* __restrict__ rgr,
                  const float* __restrict__ l1w, const float* __restrict__ l2w,
                  const float* __restrict__ p1w, const float* __restrict__ p2w,
                  const float* __restrict__ r1w, short* __restrict__ ws)
{
    int bi = blockIdx.x, l = threadIdx.x;
    const float* src; int KS, Nw, dstOff, tt;
    if      (bi <   8) { src = We1; KS = 1; Nw = 128; dstOff = WS_WE1; tt = bi; }
    else if (bi <  40) { src = We2; KS = 4; Nw = 128; dstOff = WS_WE2; tt = bi - 8; }
    else if (bi < 232) { int m = (bi - 40) >> 5;  src = rgw + m * 16384; KS = 4; Nw = 128; dstOff = WS_RGW + m * 16384; tt = (bi - 40)  & 31; }
    else if (bi < 328) { int m = (bi - 232) >> 5; src = rgr + m * 16384; KS = 4; Nw = 128; dstOff = WS_RGR + m * 16384; tt = (bi - 232) & 31; }
    else if (bi < 424) { int m = (bi - 328) >> 5; src = l1w + m * 16384; KS = 4; Nw = 128; dstOff = WS_L1  + m * 16384; tt = (bi - 328) & 31; }
    else if (bi < 520) { int m = (bi - 424) >> 5; src = l2w + m * 16384; KS = 4; Nw = 128; dstOff = WS_L2  + m * 16384; tt = (bi - 424) & 31; }
    else if (bi < 584) { src = p1w; KS = 4; Nw = 256; dstOff = WS_P1; tt = bi - 520; }
    else if (bi < 712) { src = p2w; KS = 8; Nw = 256; dstOff = WS_P2; tt = bi - 584; }
    else               { src = r1w; KS = 8; Nw = 128; dstOff = WS_R1; tt = bi - 712; }
    int nt = tt / KS, ks = tt - nt * KS;
    int kbase = ks * 32 + (l >> 4) * 8;
    int col   = nt * 16 + (l & 15);
    union { short s[8]; int4 v; } u;
#pragma unroll
    for (int j = 0; j < 8; ++j)
        u.s[j] = f2bs(src[(size_t)(kbase + j) * Nw + col]);
    *(int4*)(ws + dstOff + ((size_t)tt * 64 + l) * 8) = u.v;
}

// ================= main kernel: 1 wave = 1 graph ==========================
// A-operand layout: lane holds A[m=lane&15][k=(lane>>4)*8+j]; rows >=10 clamped to 9
// C/D layout: col = lane&15, row = (lane>>4)*4 + reg

template<int NT>
__device__ __forceinline__ void initC(f32x4* acc, const float* __restrict__ bias, int c16) {
#pragma unroll
    for (int nt = 0; nt < NT; ++nt) {
        float bv = bias[nt * 16 + c16];
        acc[nt] = (f32x4){bv, bv, bv, bv};
    }
}

// non-pipelined — used for phi/rho
template<int KS, int NT>
__device__ __forceinline__ void mm_a16(const short* __restrict__ Wf, const short* __restrict__ Ab,
                                       int ldA, int mrow, int q, int l, f32x4* acc) {
#pragma unroll
    for (int ks = 0; ks < KS; ++ks) {
        bf16x8 a = *(const bf16x8*)(Ab + mrow * ldA + ks * 32 + q * 8);
#pragma unroll
        for (int nt = 0; nt < NT; ++nt) {
            bf16x8 bv = *(const bf16x8*)(Wf + ((size_t)(nt * KS + ks) * 64 + l) * 8);
            acc[nt] = __builtin_amdgcn_mfma_f32_16x16x32_bf16(a, bv, acc[nt], 0, 0, 0);
        }
    }
}

template<int KS, int NT>
__device__ __forceinline__ void mm_a32(const short* __restrict__ Wf, const float* __restrict__ Af,
                                       int ldA, int mrow, int q, int l, f32x4* acc) {
#pragma unroll
    for (int ks = 0; ks < KS; ++ks) {
        const float* p = Af + mrow * ldA + ks * 32 + q * 8;
        f32x4 x0 = *(const f32x4*)p;
        f32x4 x1 = *(const f32x4*)(p + 4);
        bf16x8 a;
        a[0] = f2bs(x0[0]); a[1] = f2bs(x0[1]); a[2] = f2bs(x0[2]); a[3] = f2bs(x0[3]);
        a[4] = f2bs(x1[0]); a[5] = f2bs(x1[1]); a[6] = f2bs(x1[2]); a[7] = f2bs(x1[3]);
#pragma unroll
        for (int nt = 0; nt < NT; ++nt) {
            bf16x8 bv = *(const bf16x8*)(Wf + ((size_t)(nt * KS + ks) * 64 + l) * 8);
            acc[nt] = __builtin_amdgcn_mfma_f32_16x16x32_bf16(a, bv, acc[nt], 0, 0, 0);
        }
    }
}

// software-pipelined NT=8: fragments of ks+1 issue before the MFMAs of ks
template<int KS>
__device__ __forceinline__ void mm8p_a16(const short* __restrict__ Wf,
                                         const short* __restrict__ Ab, int ldA,
                                         int mrow, int q, int l, f32x4* acc)
{
    const short* ap = Ab + mrow * ldA + q * 8;
    const short* wp = Wf + l * 8;
    bf16x8 acur = *(const bf16x8*)ap;
    bf16x8 bcur[8], bnxt[8];
#pragma unroll
    for (int nt = 0; nt < 8; ++nt) bcur[nt] = *(const bf16x8*)(wp + (size_t)nt * KS * 512);
#pragma unroll
    for (int ks = 0; ks < KS; ++ks) {
        bf16x8 anxt = acur;
#pragma unroll
        for (int nt = 0; nt < 8; ++nt) bnxt[nt] = bcur[nt];
        if (ks + 1 < KS) {
            anxt = *(const bf16x8*)(ap + (ks + 1) * 32);
#pragma unroll
            for (int nt = 0; nt < 8; ++nt)
                bnxt[nt] = *(const bf16x8*)(wp + (size_t)(nt * KS + ks + 1) * 512);
        }
#pragma unroll
        for (int nt = 0; nt < 8; ++nt)
            acc[nt] = __builtin_amdgcn_mfma_f32_16x16x32_bf16(acur, bcur[nt], acc[nt], 0, 0, 0);
        acur = anxt;
#pragma unroll
        for (int nt = 0; nt < 8; ++nt) bcur[nt] = bnxt[nt];
    }
}

template<int KS>
__device__ __forceinline__ void mm8p_a32(const short* __restrict__ Wf,
                                         const float* __restrict__ Af, int ldA,
                                         int mrow, int q, int l, f32x4* acc)
{
    const float* ap = Af + mrow * ldA + q * 8;
    const short* wp = Wf + l * 8;
    auto cvt = [&](int ks) {
        f32x4 x0 = *(const f32x4*)(ap + ks * 32);
        f32x4 x1 = *(const f32x4*)(ap + ks * 32 + 4);
        bf16x8 a;
        a[0] = f2bs(x0[0]); a[1] = f2bs(x0[1]); a[2] = f2bs(x0[2]); a[3] = f2bs(x0[3]);
        a[4] = f2bs(x1[0]); a[5] = f2bs(x1[1]); a[6] = f2bs(x1[2]); a[7] = f2bs(x1[3]);
        return a;
    };
    bf16x8 acur = cvt(0);
    bf16x8 bcur[8], bnxt[8];
#pragma unroll
    for (int nt = 0; nt < 8; ++nt) bcur[nt] = *(const bf16x8*)(wp + (size_t)nt * KS * 512);
#pragma unroll
    for (int ks = 0; ks < KS; ++ks) {
        bf16x8 anxt = acur;
#pragma unroll
        for (int nt = 0; nt < 8; ++nt) bnxt[nt] = bcur[nt];
        if (ks + 1 < KS) {
            anxt = cvt(ks + 1);
#pragma unroll
            for (int nt = 0; nt < 8; ++nt)
                bnxt[nt] = *(const bf16x8*)(wp + (size_t)(nt * KS + ks + 1) * 512);
        }
#pragma unroll
        for (int nt = 0; nt < 8; ++nt)
            acc[nt] = __builtin_amdgcn_mfma_f32_16x16x32_bf16(acur, bcur[nt], acc[nt], 0, 0, 0);
        acur = anxt;
#pragma unroll
        for (int nt = 0; nt < 8; ++nt) bcur[nt] = bnxt[nt];
    }
}

// store C tiles as bf16 into LDS (row-major, ldD elements), rows >= 10 dropped
template<int NT, bool RELU>
__device__ __forceinline__ void storeC16(const f32x4* acc, short* __restrict__ dst,
                                         int ldD, int q, int c16) {
#pragma unroll
    for (int nt = 0; nt < NT; ++nt) {
#pragma unroll
        for (int i = 0; i < 4; ++i) {
            int r = q * 4 + i;
            if (r < 10) {
                float v = acc[nt][i];
                if (RELU) v = fmaxf(v, 0.f);
                dst[r * ldD + nt * 16 + c16] = f2bs(v);
            }
        }
    }
}

#define HLD  132   // Hf row stride (f32), 528 B — 4-bank row stagger
#define GLD  264   // Gb row stride (bf16), 528 B — slots S0=+0, S1=+136
#define H2LD 136   // H2 row stride (bf16), 272 B — 4-bank row stagger

__global__ __launch_bounds__(64, 2)
void gcn_main(const float* __restrict__ A, const float* __restrict__ X,
              const int* __restrict__ home_mask,
              const float* __restrict__ be1, const float* __restrict__ be2,
              const float* __restrict__ rgcn_b,
              const float* __restrict__ l1b, const float* __restrict__ l2b,
              const float* __restrict__ ln_g, const float* __restrict__ ln_b,
              const float* __restrict__ p1b, const float* __restrict__ p2b,
              const float* __restrict__ r1b, const float* __restrict__ r2w,
              const short* __restrict__ ws, float* __restrict__ out)
{
    const int b   = blockIdx.x;
    const int l   = threadIdx.x;       // 0..63
    const int q   = l >> 4;
    const int c16 = l & 15;
    const int mrow = (c16 < 10) ? c16 : 9;    // A-row clamp (C rows>=10 ignored)

    // Buffer flow invariant: every phase's write-buffer is disjoint from its
    // read-buffers (no in-place phases — that pattern broke round 4).
    __shared__ __align__(16) float HfS[N_ * HLD];     // residual H, fp32 (5280 B)
    __shared__ __align__(16) short GbS[N_ * GLD];     // S0/S1 slots + phi1 rows (5280 B)
    __shared__ __align__(16) short H2S[N_ * H2LD];    // H2 out; later RhoS overlay (2720 B)
    __shared__ float AabsS[100], M1S[100];
    __shared__ float invc0S[N_], invc1S[N_];
    __shared__ float hmfS[16], awfS[16];

    short* S0 = GbS;          // cols 0..127 of slot 0
    short* S1 = GbS + 136;    // slot 1, base 272 B (16-aligned)
    short* RhoS = H2S;        // overlay: H2S dead after last agg; rho rows stride 256

    // ---- stage A, home_mask ----
    {
        const float* Ab = A + (size_t)b * 100;
#pragma unroll
        for (int e = l; e < 100; e += 64) {
            float a = Ab[e];
            AabsS[e] = fabsf(a);
            M1S[e]  = (a > 0.f) ? 1.f : 0.f;
        }
        if (l < 16) {
            float hm = 0.f, aw = 0.f;
            if (l < 10) { hm = (float)home_mask[b * N_ + l]; aw = 1.f - hm; }
            hmfS[l] = hm; awfS[l] = aw;
        }
        if (l < 10) {
            float c1 = 0.f;
#pragma unroll
            for (int i = 0; i < 10; ++i) c1 += M1S[i * 10 + l];
            invc1S[l] = 1.f / fmaxf(c1, 1.f);
            invc0S[l] = 1.f / fmaxf(10.f - c1, 1.f);
        }
    }

    // ---- embed1: H1 = relu(X@We1 + be1) -> S0 ----
    {
        f32x4 acc[8];
        initC<8>(acc, be1, c16);
        const float* xg = X + (size_t)b * (N_ * DIN_) + mrow * DIN_ + q * 8;
        f32x4 x0 = *(const f32x4*)xg;
        f32x4 x1 = *(const f32x4*)(xg + 4);
        bf16x8 a;
        a[0] = f2bs(x0[0]); a[1] = f2bs(x0[1]); a[2] = f2bs(x0[2]); a[3] = f2bs(x0[3]);
        a[4] = f2bs(x1[0]); a[5] = f2bs(x1[1]); a[6] = f2bs(x1[2]); a[7] = f2bs(x1[3]);
#pragma unroll
        for (int nt = 0; nt < 8; ++nt) {
            bf16x8 bv = *(const bf16x8*)(ws + WS_WE1 + ((size_t)nt * 64 + l) * 8);
            acc[nt] = __builtin_amdgcn_mfma_f32_16x16x32_bf16(a, bv, acc[nt], 0, 0, 0);
        }
        storeC16<8, true>(acc, S0, GLD, q, c16);
    }
    // ---- embed2: H = H1@We2 + be2 -> Hf (fp32) [reads S0, writes HfS] ----
    {
        f32x4 acc[8];
        initC<8>(acc, be2, c16);
        mm8p_a16<4>(ws + WS_WE2, S0, GLD, mrow, q, l, acc);
#pragma unroll
        for (int nt = 0; nt < 8; ++nt)
#pragma unroll
            for (int i = 0; i < 4; ++i) {
                int r = q * 4 + i;
                if (r < 10) HfS[r * HLD + nt * 16 + c16] = acc[nt][i];
            }
    }

    const v2f lg2 = *(const v2f*)(ln_g + 2 * l);
    const v2f lb2 = *(const v2f*)(ln_b + 2 * l);

    // ---- layers ----
    for (int ll = 0; ll < L_; ++ll) {
        // means [reads HfS; writes S0=mean0, S1=mean1 — both slots dead here]
        {
            v2f hv[N_];
#pragma unroll
            for (int i = 0; i < N_; ++i) hv[i] = *(const v2f*)(HfS + i * HLD + 2 * l);
            v2f st = hv[0];
#pragma unroll
            for (int i = 1; i < N_; ++i) st += hv[i];
#pragma unroll
            for (int j = 0; j < N_; ++j) {
                v2f s1 = splat2(0.f);
#pragma unroll
                for (int i = 0; i < N_; ++i) s1 = fma2(splat2(M1S[i * 10 + j]), hv[i], s1);
                v2f m0 = (st - s1) * splat2(invc0S[j]);
                v2f m1 = s1 * splat2(invc1S[j]);
                short2 w0; w0.x = f2bs(m0.x); w0.y = f2bs(m0.y);
                short2 w1; w1.x = f2bs(m1.x); w1.y = f2bs(m1.y);
                *(short2*)(S0 + j * GLD + 2 * l) = w0;
                *(short2*)(S1 + j * GLD + 2 * l) = w1;
            }
        }
        // H2 = mean0@W0 + mean1@W1 + H@root + b [reads S0,S1,HfS; writes H2S]
        {
            f32x4 acc[8];
            initC<8>(acc, rgcn_b + ll * D_, c16);
            mm8p_a16<4>(ws + WS_RGW + (size_t)(ll * 2 + 0) * 16384, S0, GLD, mrow, q, l, acc);
            mm8p_a16<4>(ws + WS_RGW + (size_t)(ll * 2 + 1) * 16384, S1, GLD, mrow, q, l, acc);
            mm8p_a32<4>(ws + WS_RGR + (size_t)ll * 16384, HfS, HLD, mrow, q, l, acc);
            storeC16<8, false>(acc, H2S, H2LD, q, c16);
        }
        // agg[i] = sum_j |A[i,j]| * H2[j] + LayerNorm + relu [reads H2S; writes S0]
        {
            v2f ag[N_];
#pragma unroll
            for (int i = 0; i < N_; ++i) ag[i] = splat2(0.f);
#pragma unroll
            for (int j = 0; j < N_; ++j) {
                short2 hh = *(const short2*)(H2S + j * H2LD + 2 * l);
                v2f h2; h2.x = bs2f(hh.x); h2.y = bs2f(hh.y);
#pragma unroll
                for (int i = 0; i < N_; ++i)
                    ag[i] = fma2(splat2(AabsS[i * 10 + j]), h2, ag[i]);
            }
#pragma unroll
            for (int i = 0; i < N_; ++i) {
                float s  = ag[i].x + ag[i].y;
                float ss = fmaf(ag[i].x, ag[i].x, ag[i].y * ag[i].y);
#pragma unroll
                for (int off = 32; off > 0; off >>= 1) {
                    s  += __shfl_xor(s,  off);
                    ss += __shfl_xor(ss, off);
                }
                float mu   = s * (1.f / 128.f);
                float var  = ss * (1.f / 128.f) - mu * mu;
                float rstd = rsqrtf(var + EPS_);
                v2f v = fma2((ag[i] - splat2(mu)) * splat2(rstd), lg2, lb2);
                short2 wv; wv.x = f2bs(fmaxf(v.x, 0.f)); wv.y = f2bs(fmaxf(v.y, 0.f));
                *(short2*)(S0 + i * GLD + 2 * l) = wv;
            }
        }
        // MLP1: relu(LNout @ l1w + l1b) [reads S0; writes S1]
        {
            f32x4 acc[8];
            initC<8>(acc, l1b + ll * D_, c16);
            mm8p_a16<4>(ws + WS_L1 + (size_t)ll * 16384, S0, GLD, mrow, q, l, acc);
            storeC16<8, true>(acc, S1, GLD, q, c16);
        }
        // MLP2: hidden @ l2w + l2b [reads S1; accumulates into HfS]
        {
            f32x4 acc[8];
            initC<8>(acc, l2b + ll * D_, c16);
            mm8p_a16<4>(ws + WS_L2 + (size_t)ll * 16384, S1, GLD, mrow, q, l, acc);
#pragma unroll
            for (int nt = 0; nt < 8; ++nt)
#pragma unroll
                for (int i = 0; i < 4; ++i) {
                    int r = q * 4 + i;
                    if (r < 10) HfS[r * HLD + nt * 16 + c16] += acc[nt][i];
                }
        }
    }

    // ---- phi1: relu(H @ p1w + p1b) [reads HfS; writes GbS cols 0..255] ----
    {
        f32x4 acc[16];
        initC<16>(acc, p1b, c16);
        mm_a32<4, 16>(ws + WS_P1, HfS, HLD, mrow, q, l, acc);
        storeC16<16, true>(acc, GbS, GLD, q, c16);
    }
    // ---- phi2 + masked column sums [reads GbS; writes RhoS(=H2S)] ----
    {
        f32x4 acc[16];
        initC<16>(acc, p2b, c16);
        mm_a16<8, 16>(ws + WS_P2, GbS, GLD, mrow, q, l, acc);
        float hm0 = hmfS[q * 4 + 0], hm1 = hmfS[q * 4 + 1], hm2 = hmfS[q * 4 + 2], hm3 = hmfS[q * 4 + 3];
        float aw0 = awfS[q * 4 + 0], aw1 = awfS[q * 4 + 1], aw2 = awfS[q * 4 + 2], aw3 = awfS[q * 4 + 3];
#pragma unroll
        for (int t = 0; t < 16; ++t) {
            float v0 = fmaxf(acc[t][0], 0.f), v1 = fmaxf(acc[t][1], 0.f);
            float v2 = fmaxf(acc[t][2], 0.f), v3 = fmaxf(acc[t][3], 0.f);
            float hp = hm0 * v0 + hm1 * v1 + hm2 * v2 + hm3 * v3;
            float ap = aw0 * v0 + aw1 * v1 + aw2 * v2 + aw3 * v3;
            hp += __shfl_xor(hp, 16); hp += __shfl_xor(hp, 32);
            ap += __shfl_xor(ap, 16); ap += __shfl_xor(ap, 32);
            if (l < 16) {
                RhoS[t * 16 + l]       = f2bs(hp);
                RhoS[256 + t * 16 + l] = f2bs(ap);
            }
        }
    }
    // ---- rho: relu([hs;aws] @ r1w + r1b) @ r2w, antisym difference ----
    {
        f32x4 acc[8];
        initC<8>(acc, r1b, c16);
        const int rr = (c16 < 2) ? c16 : 0;
        mm_a16<8, 8>(ws + WS_R1, RhoS, 256, rr, q, l, acc);
        float d = 0.f;
        if (q == 0) {
#pragma unroll
            for (int t = 0; t < 8; ++t) {
                float vh = fmaxf(acc[t][0], 0.f);
                float va = fmaxf(acc[t][1], 0.f);
                d = fmaf(vh - va, r2w[t * 16 + c16], d);
            }
        }
#pragma unroll
        for (int off = 32; off > 0; off >>= 1) d += __shfl_xor(d, off);
        if (l == 0) out[b] = 0.5f + 0.5f * tanhf(d);
    }
}

extern "C" void kernel_launch(void* const* d_in, const int* in_sizes, int n_in,
                              void* d_out, int out_size, void* d_ws, size_t ws_size,
                              hipStream_t stream) {
    const float* A         = (const float*)d_in[0];
    const float* X         = (const float*)d_in[1];
    const int*   home_mask = (const int*)  d_in[2];
    const float* We1       = (const float*)d_in[3];
    const float* be1       = (const float*)d_in[4];
    const float* We2       = (const float*)d_in[5];
    const float* be2       = (const float*)d_in[6];
    const float* rgcn_w    = (const float*)d_in[7];
    const float* rgcn_root = (const float*)d_in[8];
    const float* rgcn_b    = (const float*)d_in[9];
    const float* l1w       = (const float*)d_in[10];
    const float* l1b       = (const float*)d_in[11];
    const float* l2w       = (const float*)d_in[12];
    const float* l2b       = (const float*)d_in[13];
    const float* ln_g      = (const float*)d_in[14];
    const float* ln_b      = (const float*)d_in[15];
    const float* p1w       = (const float*)d_in[16];
    const float* p1b       = (const float*)d_in[17];
    const float* p2w       = (const float*)d_in[18];
    const float* p2b       = (const float*)d_in[19];
    const float* r1w       = (const float*)d_in[20];
    const float* r1b       = (const float*)d_in[21];
    const float* r2w       = (const float*)d_in[22];

    short* ws = (short*)d_ws;

    prep_weights<<<776, 64, 0, stream>>>(We1, We2, rgcn_w, rgcn_root,
                                         l1w, l2w, p1w, p2w, r1w, ws);
    gcn_main<<<B_, 64, 0, stream>>>(A, X, home_mask, be1, be2, rgcn_b,
                                    l1b, l2b, ln_g, ln_b, p1b, p2b,
                                    r1b, r2w, ws, (float*)d_out);
}